// Round 19
// baseline (205.128 us; speedup 1.0000x reference)
//
#include <hip/hip_runtime.h>
#include <hip/hip_bf16.h>
#include <stdint.h>

#define KTOT 8192
#define BM 128
#define BK 128
#define KSPLIT 4
#define KCHUNK (KTOT / KSPLIT)   // 2048
#define NIT (KCHUNK / BK)        // 16
#define TILE_BYTES (BM * BK * 2) // 32 KiB blocked-A tile image
#define NMBLK (KTOT / BM)        // 64

typedef __attribute__((ext_vector_type(8))) __bf16 bf16x8;
typedef __attribute__((ext_vector_type(4))) float f32x4;

__device__ __forceinline__ unsigned short f2bf(float f) {
  union { float f; unsigned int u; } a;
  a.f = f;
  unsigned int r = (a.u + 0x7fffu + ((a.u >> 16) & 1u)) >> 16;
  return (unsigned short)r;
}

__device__ __forceinline__ uint2 pack4(f32x4 v) {
  union { unsigned short h[4]; uint2 u; } pk;
  pk.h[0] = f2bf(v[0]); pk.h[1] = f2bf(v[1]);
  pk.h[2] = f2bf(v[2]); pk.h[3] = f2bf(v[3]);
  return pk.u;
}

// Barrier that drains LDS only — global prefetches stay in flight (T4).
__device__ __forceinline__ void block_bar() {
  asm volatile("s_waitcnt lgkmcnt(0)" ::: "memory");
  __builtin_amdgcn_s_barrier();
  __builtin_amdgcn_sched_barrier(0);
}

// x_p / x_n [8192][64] f32 -> xt [64][8192] bf16 (transposed), one dispatch.
__global__ __launch_bounds__(256) void xpose_both(const float* __restrict__ xp,
                                                  const float* __restrict__ xn,
                                                  __hip_bfloat16* __restrict__ xt) {
  __shared__ unsigned short tile[64][72];
  const int b = blockIdx.x;
  const float* x = (b < 128) ? xp : xn;
  unsigned short* dst = (unsigned short*)xt + (b < 128 ? 0 : (size_t)64 * KTOT);
  const int r0 = (b & 127) * 64;
  const int t = threadIdx.x;
  const int a = t >> 4;
  const int c4 = (t & 15) * 4;
#pragma unroll
  for (int rep = 0; rep < 4; ++rep) {
    int r = a + rep * 16;
    f32x4 v = __builtin_nontemporal_load(
        reinterpret_cast<const f32x4*>(x + (size_t)(r0 + r) * 64 + c4));
    tile[c4 + 0][r] = f2bf(v[0]);
    tile[c4 + 1][r] = f2bf(v[1]);
    tile[c4 + 2][r] = f2bf(v[2]);
    tile[c4 + 3][r] = f2bf(v[3]);
  }
  __syncthreads();
#pragma unroll
  for (int rep = 0; rep < 4; ++rep) {
    int j = a + rep * 16;
    uint2 v = *reinterpret_cast<const uint2*>(&tile[j][c4]);
    *reinterpret_cast<uint2*>(dst + (size_t)j * KTOT + r0 + c4) = v;
  }
}

// part[kc][col][row] partials of C = A @ B, BT[128][8192] bf16. BM=128,
// grid 256 = 1 block/CU. A reg->bf16->LDS (XOR swizzle) dbuf, depth-2 reg
// prefetch; B direct global->reg; lgkm-only barriers; K-phase rotation;
// XCD-affine kc; regular (L3-retained) part stores. Blocks with kc < kcb
// also emit packed bf16 tile images to ablk[kc][mblk][tile].
__global__ __launch_bounds__(512, 2) void gemm_part(
    const float* __restrict__ A, const __hip_bfloat16* __restrict__ BTv,
    float* __restrict__ part, unsigned char* __restrict__ ablk, int kcb) {
  constexpr int SZ_A = BM * BK * 2;   // 32 KiB
  __shared__ __align__(16) unsigned char smem[2 * SZ_A];   // 64 KiB
  const unsigned short* BT = (const unsigned short*)BTv;

  const int bid = blockIdx.x;
  const int kc = (bid & 7) >> 1;                 // XCD-affine K-chunk
  const int mblk = ((bid >> 3) << 1) | (bid & 1); // 0..63
  const int r0 = mblk * BM;
  const int kbase = kc * KCHUNK;
  const int it0 = mblk & (NIT - 1);              // K-phase rotation

  const int t = threadIdx.x;
  const int l = t & 63;
  const int w = t >> 6;

  const float* aptr[8];
  int loff[8];
#pragma unroll
  for (int r = 0; r < 8; ++r) {
    int idx = t + r * 512;
    int m = idx >> 5, c4 = idx & 31;
    aptr[r] = A + (size_t)(r0 + m) * KTOT + kbase + c4 * 4;
    loff[r] = m * 256 + ((c4 * 8) ^ ((m & 7) << 4));
  }
  unsigned char* tb0 = (kc < kcb)
      ? ablk + (size_t)(kc * NMBLK + mblk) * NIT * TILE_BYTES : nullptr;

  const int lr = l & 15;
  const int g = l >> 4;
  const int col = w * 16 + lr;
  const unsigned short* bptr = BT + (size_t)col * KTOT + kbase + g * 8;
  const int asw = (lr & 7) << 4;

  f32x4 acc[8];
  const f32x4 fzero = {0.f, 0.f, 0.f, 0.f};
#pragma unroll
  for (int mt = 0; mt < 8; ++mt) acc[mt] = fzero;

  f32x4 av0[8], av1[8];
  bf16x8 Bf0[4], Bf1[4];
  unsigned char* lds0 = smem;
  unsigned char* lds1 = smem + SZ_A;

  auto kof = [&](int s) { return ((s + it0) & (NIT - 1)) * BK; };

#define LOAD_A(AV, K0)                                                        \
  _Pragma("unroll") for (int r = 0; r < 8; ++r)                               \
      AV[r] = __builtin_nontemporal_load(                                     \
          reinterpret_cast<const f32x4*>(aptr[r] + (K0)));
#define LOAD_B(BF, K0)                                                        \
  _Pragma("unroll") for (int ks = 0; ks < 4; ++ks)                            \
      BF[ks] = *reinterpret_cast<const bf16x8*>(bptr + (K0) + ks * 32);
#define WRITE_A(LDS, AV, RS)                                                  \
  _Pragma("unroll") for (int r = 0; r < 8; ++r) {                             \
    uint2 pk_ = pack4(AV[r]);                                                 \
    *reinterpret_cast<uint2*>((LDS) + loff[r]) = pk_;                         \
    if (tb0)                                                                  \
      *reinterpret_cast<uint2*>(tb0 + (size_t)(RS) * TILE_BYTES + loff[r]) =  \
          pk_;                                                                \
  }
#define COMPUTE(LDS, BF)                                                      \
  _Pragma("unroll") for (int ks = 0; ks < 4; ++ks) {                          \
    _Pragma("unroll") for (int mt = 0; mt < 8; ++mt) {                        \
      bf16x8 af_ = *reinterpret_cast<const bf16x8*>(                          \
          (LDS) + (mt * 16 + lr) * 256 + ((ks * 64 + g * 16) ^ asw));         \
      acc[mt] = __builtin_amdgcn_mfma_f32_16x16x32_bf16(af_, BF[ks], acc[mt], \
                                                        0, 0, 0);             \
    }                                                                         \
  }

  LOAD_A(av0, kof(0)); LOAD_B(Bf0, kof(0));
  LOAD_A(av1, kof(1)); LOAD_B(Bf1, kof(1));
  WRITE_A(lds0, av0, it0);
  block_bar();

#pragma unroll 1
  for (int s = 0; s < NIT; s += 2) {
    if (s + 1 < NIT) { WRITE_A(lds1, av1, (s + 1 + it0) & (NIT - 1)); }
    if (s + 2 < NIT) { LOAD_A(av0, kof(s + 2)); }
    COMPUTE(lds0, Bf0);
    if (s + 2 < NIT) { LOAD_B(Bf0, kof(s + 2)); }
    if (s + 1 < NIT) block_bar();
    if (s + 1 < NIT) {
      if (s + 2 < NIT) { WRITE_A(lds0, av0, (s + 2 + it0) & (NIT - 1)); }
      if (s + 3 < NIT) { LOAD_A(av1, kof(s + 3)); }
      COMPUTE(lds1, Bf1);
      if (s + 3 < NIT) { LOAD_B(Bf1, kof(s + 3)); }
      if (s + 2 < NIT) block_bar();
    }
  }

  float* pp = part + (size_t)(kc * 128 + col) * KTOT + r0 + g * 4;
#pragma unroll
  for (int mt = 0; mt < 8; ++mt)
    *reinterpret_cast<f32x4*>(pp + mt * 16) = acc[mt];
#undef LOAD_A
#undef WRITE_A
}

// G3 hybrid: blocks with kc < kcb read A from blocked bf16 tile images
// (dense 512 KB slab); others fall back to the f32 comb read. Same
// pipeline structure either way.
__global__ __launch_bounds__(512, 2) void gemm_mixed(
    const float* __restrict__ A, const unsigned char* __restrict__ ablk,
    int kcb, const __hip_bfloat16* __restrict__ BTv, float* __restrict__ part) {
  constexpr int SZ_A = BM * BK * 2;
  __shared__ __align__(16) unsigned char smem[2 * SZ_A];
  const unsigned short* BT = (const unsigned short*)BTv;

  const int bid = blockIdx.x;
  const int kc = (bid & 7) >> 1;
  const int mblk = ((bid >> 3) << 1) | (bid & 1);
  const int r0 = mblk * BM;
  const int kbase = kc * KCHUNK;
  const int it0 = mblk & (NIT - 1);

  const int t = threadIdx.x;
  const int l = t & 63;
  const int w = t >> 6;

  const float* aptr[8];
  int loff[8];
#pragma unroll
  for (int r = 0; r < 8; ++r) {
    int idx = t + r * 512;
    int m = idx >> 5, c4 = idx & 31;
    aptr[r] = A + (size_t)(r0 + m) * KTOT + kbase + c4 * 4;
    loff[r] = m * 256 + ((c4 * 8) ^ ((m & 7) << 4));
  }
  const unsigned char* tb0 =
      ablk + (size_t)(kc * NMBLK + mblk) * NIT * TILE_BYTES;

  const int lr = l & 15;
  const int g = l >> 4;
  const int col = w * 16 + lr;
  const unsigned short* bptr = BT + (size_t)col * KTOT + kbase + g * 8;
  const int asw = (lr & 7) << 4;

  f32x4 acc[8];
  const f32x4 fzero = {0.f, 0.f, 0.f, 0.f};
#pragma unroll
  for (int mt = 0; mt < 8; ++mt) acc[mt] = fzero;

  unsigned char* lds0 = smem;
  unsigned char* lds1 = smem + SZ_A;
  bf16x8 Bf0[4], Bf1[4];

  auto kof = [&](int s) { return ((s + it0) & (NIT - 1)) * BK; };
  auto rs = [&](int s) { return (s + it0) & (NIT - 1); };

#define LOAD_B(BF, K0)                                                        \
  _Pragma("unroll") for (int ks = 0; ks < 4; ++ks)                            \
      BF[ks] = *reinterpret_cast<const bf16x8*>(bptr + (K0) + ks * 32);
#define COMPUTE(LDS, BF)                                                      \
  _Pragma("unroll") for (int ks = 0; ks < 4; ++ks) {                          \
    _Pragma("unroll") for (int mt = 0; mt < 8; ++mt) {                        \
      bf16x8 af_ = *reinterpret_cast<const bf16x8*>(                          \
          (LDS) + (mt * 16 + lr) * 256 + ((ks * 64 + g * 16) ^ asw));         \
      acc[mt] = __builtin_amdgcn_mfma_f32_16x16x32_bf16(af_, BF[ks], acc[mt], \
                                                        0, 0, 0);             \
    }                                                                         \
  }

  if (kc < kcb) {
    // ---- blocked path: dense bf16 tile images ----
    uint2 bv0[8], bv1[8];
#define LOAD_T(BV, RS)                                                        \
  _Pragma("unroll") for (int r = 0; r < 8; ++r)                               \
      BV[r] = *reinterpret_cast<const uint2*>(                                \
          tb0 + (size_t)(RS) * TILE_BYTES + loff[r]);
#define WRITE_T(LDS, BV)                                                      \
  _Pragma("unroll") for (int r = 0; r < 8; ++r)                               \
      *reinterpret_cast<uint2*>((LDS) + loff[r]) = BV[r];
    LOAD_T(bv0, rs(0)); LOAD_B(Bf0, kof(0));
    LOAD_T(bv1, rs(1)); LOAD_B(Bf1, kof(1));
    WRITE_T(lds0, bv0);
    block_bar();
#pragma unroll 1
    for (int s = 0; s < NIT; s += 2) {
      if (s + 1 < NIT) { WRITE_T(lds1, bv1); }
      if (s + 2 < NIT) { LOAD_T(bv0, rs(s + 2)); }
      COMPUTE(lds0, Bf0);
      if (s + 2 < NIT) { LOAD_B(Bf0, kof(s + 2)); }
      if (s + 1 < NIT) block_bar();
      if (s + 1 < NIT) {
        if (s + 2 < NIT) { WRITE_T(lds0, bv0); }
        if (s + 3 < NIT) { LOAD_T(bv1, rs(s + 3)); }
        COMPUTE(lds1, Bf1);
        if (s + 3 < NIT) { LOAD_B(Bf1, kof(s + 3)); }
        if (s + 2 < NIT) block_bar();
      }
    }
#undef LOAD_T
#undef WRITE_T
  } else {
    // ---- f32 comb fallback (R18 path) ----
    f32x4 av0[8], av1[8];
#define LOAD_A(AV, K0)                                                        \
  _Pragma("unroll") for (int r = 0; r < 8; ++r)                               \
      AV[r] = __builtin_nontemporal_load(                                     \
          reinterpret_cast<const f32x4*>(aptr[r] + (K0)));
#define WRITE_A(LDS, AV)                                                      \
  _Pragma("unroll") for (int r = 0; r < 8; ++r)                               \
      *reinterpret_cast<uint2*>((LDS) + loff[r]) = pack4(AV[r]);
    LOAD_A(av0, kof(0)); LOAD_B(Bf0, kof(0));
    LOAD_A(av1, kof(1)); LOAD_B(Bf1, kof(1));
    WRITE_A(lds0, av0);
    block_bar();
#pragma unroll 1
    for (int s = 0; s < NIT; s += 2) {
      if (s + 1 < NIT) { WRITE_A(lds1, av1); }
      if (s + 2 < NIT) { LOAD_A(av0, kof(s + 2)); }
      COMPUTE(lds0, Bf0);
      if (s + 2 < NIT) { LOAD_B(Bf0, kof(s + 2)); }
      if (s + 1 < NIT) block_bar();
      if (s + 1 < NIT) {
        if (s + 2 < NIT) { WRITE_A(lds0, av0); }
        if (s + 3 < NIT) { LOAD_A(av1, kof(s + 3)); }
        COMPUTE(lds1, Bf1);
        if (s + 3 < NIT) { LOAD_B(Bf1, kof(s + 3)); }
        if (s + 2 < NIT) block_bar();
      }
    }
#undef LOAD_A
#undef WRITE_A
  }

  float* pp = part + (size_t)(kc * 128 + col) * KTOT + r0 + g * 4;
#pragma unroll
  for (int mt = 0; mt < 8; ++mt)
    *reinterpret_cast<f32x4*>(pp + mt * 16) = acc[mt];
#undef LOAD_B
#undef COMPUTE
}

// Combine KSPLIT partials + epilogue, separate halves (lo: cols 0-63, hi: 64-127).
__global__ __launch_bounds__(256) void reduce_sep(
    const float* __restrict__ part, float* __restrict__ out,
    const float* s_lo_p, const float* s_hi_p,
    const float* __restrict__ add_ptr, const float* add_s_p,
    __hip_bfloat16* bt_lo, __hip_bfloat16* bt_hi,
    int base_lo, int base_hi, int accum) {
  const int t = threadIdx.x;
  const int col = t & 127;
  const int rbase = blockIdx.x * 32 + (t >> 7) * 16;
  const float* p0 = part + (size_t)col * KTOT + rbase;
  const bool hi = col >= 64;
  const int col64 = hi ? col - 64 : col;
  __hip_bfloat16* bt = hi ? bt_hi : bt_lo;
  const int obase = hi ? base_hi : base_lo;
  const float s = hi ? (s_hi_p ? *s_hi_p : 0.f) : (s_lo_p ? *s_lo_p : 0.f);
  const float was = add_s_p ? *add_s_p : 0.f;
#pragma unroll
  for (int i = 0; i < 4; ++i) {
    f32x4 c = *reinterpret_cast<const f32x4*>(p0 + 4 * i);
#pragma unroll
    for (int k = 1; k < KSPLIT; ++k)
      c += *reinterpret_cast<const f32x4*>(p0 + (size_t)k * 128 * KTOT + 4 * i);
    if (bt)
      *reinterpret_cast<uint2*>((unsigned short*)bt + (size_t)col64 * KTOT + rbase + 4 * i) =
          pack4(c);
    if (obase >= 0) {
#pragma unroll
      for (int j = 0; j < 4; ++j) {
        int row = rbase + 4 * i + j;
        float v = s * c[j];
        if (add_ptr && !hi) v = fmaf(was, add_ptr[(size_t)row * 64 + col64], v);
        if (accum) v += out[(size_t)row * 128 + obase + col64];
        out[(size_t)row * 128 + obase + col64] = v;
      }
    }
  }
}

// Combine partials + cross-half epilogue: out[:,64+c] = sl*lo[c] + sh*hi[c];
// bt_lo = raw lo (bf16 transposed).
__global__ __launch_bounds__(256) void reduce_comb(
    const float* __restrict__ part, float* __restrict__ out,
    const float* s_lo_p, const float* s_hi_p, __hip_bfloat16* bt_lo) {
  const int t = threadIdx.x;
  const int c = t & 63;
  const int rbase = blockIdx.x * 32 + (t >> 6) * 8;
  const float* pl = part + (size_t)c * KTOT + rbase;
  const float* ph = part + (size_t)(c + 64) * KTOT + rbase;
  const float sl = *s_lo_p, sh = *s_hi_p;
#pragma unroll
  for (int i = 0; i < 2; ++i) {
    f32x4 lo = *reinterpret_cast<const f32x4*>(pl + 4 * i);
    f32x4 hv = *reinterpret_cast<const f32x4*>(ph + 4 * i);
#pragma unroll
    for (int k = 1; k < KSPLIT; ++k) {
      lo += *reinterpret_cast<const f32x4*>(pl + (size_t)k * 128 * KTOT + 4 * i);
      hv += *reinterpret_cast<const f32x4*>(ph + (size_t)k * 128 * KTOT + 4 * i);
    }
    *reinterpret_cast<uint2*>((unsigned short*)bt_lo + (size_t)c * KTOT + rbase + 4 * i) =
        pack4(lo);
#pragma unroll
    for (int j = 0; j < 4; ++j) {
      int row = rbase + 4 * i + j;
      out[(size_t)row * 128 + 64 + c] = sl * lo[j] + sh * hv[j];
    }
  }
}

extern "C" void kernel_launch(void* const* d_in, const int* in_sizes, int n_in,
                              void* d_out, int out_size, void* d_ws, size_t ws_size,
                              hipStream_t stream) {
  const float* A_p = (const float*)d_in[0];
  const float* A_n = (const float*)d_in[1];
  const float* x_p = (const float*)d_in[2];
  const float* x_n = (const float*)d_in[3];
  const float* w_p = (const float*)d_in[4];  // [3]
  const float* w_n = (const float*)d_in[5];  // [3]
  float* out = (float*)d_out;                // [8192][128]

  // ws layout:
  //   BTbig [192][8192] bf16 (3 MiB) | B3T [128][8192] bf16 (2 MiB)
  //   part  [KSPLIT][128][8192] f32 (16 MiB)
  //   ablk  blocked bf16 A_p: kcb * 32 MiB  (kcb = 0..4 tiers by ws_size)
  __hip_bfloat16* BTbig = (__hip_bfloat16*)d_ws;
  __hip_bfloat16* B3T = BTbig + (size_t)192 * KTOT;
  float* part = (float*)(B3T + (size_t)128 * KTOT);
  unsigned char* ablk = (unsigned char*)(part + (size_t)KSPLIT * 128 * KTOT);
  const size_t base_need = (size_t)192 * KTOT * 2 + (size_t)128 * KTOT * 2 +
                           (size_t)KSPLIT * 128 * KTOT * 4;
  const size_t per_kc = (size_t)NMBLK * NIT * TILE_BYTES;   // 32 MiB
  size_t avail = ws_size > base_need ? ws_size - base_need : 0;
  int kcb = (int)(avail / per_kc);
  if (kcb > KSPLIT) kcb = KSPLIT;

  xpose_both<<<256, 256, 0, stream>>>(x_p, x_n, BTbig);

  // G1: [P1|Y1] = A_p @ [x_p|x_n]  (+ emit blocked bf16 A_p for kc < kcb)
  gemm_part<<<256, 512, 0, stream>>>(A_p, BTbig, part, ablk, kcb);
  reduce_sep<<<256, 256, 0, stream>>>(part, out, w_p + 1, nullptr, x_p, w_p + 0,
                                      B3T, BTbig + (size_t)128 * KTOT, 0, -1, 0);

  // G2': [T1|T3] = A_n @ [x_n|Y1]
  gemm_part<<<256, 512, 0, stream>>>(A_n, BTbig + (size_t)64 * KTOT, part,
                                     nullptr, 0);
  reduce_comb<<<256, 256, 0, stream>>>(part, out, w_n + 0, w_n + 2,
                                       B3T + (size_t)64 * KTOT);

  // G3: [P2|T2] = A_p @ [P1|T1] — blocked A for kc < kcb, f32 comb otherwise
  gemm_mixed<<<256, 512, 0, stream>>>(A_p, ablk, kcb, B3T, part);
  reduce_sep<<<256, 256, 0, stream>>>(part, out, w_p + 2, w_n + 1, nullptr, nullptr,
                                      nullptr, nullptr, 0, 64, 1);
}